// Round 5
// baseline (504.350 us; speedup 1.0000x reference)
//
#include <hip/hip_runtime.h>
#include <math.h>

#define HH 128
#define WW 128
#define NIMG 4
#define PP 11
#define KSIM 16
#define STRIDE_S 3
#define VRAD 32
#define WINW 65             // 2V+1
#define NTASK (WINW*9)      // 585 tasks: (drx, 8-wide dc strip)
#define HREF 40
#define WREF 40
#define NPOS 118            // H-P+1
#define WROWS 75            // 2V+P
#define WPITCH 84           // rows 336B (16B-multiple); c0=8g -> 32B-aligned
#define NGROUP (NIMG*HREF*WREF) // 6400
#define EPS_E 30.25f        // n*alpha^2*sigma^2
#define DE_C 151.25f        // D+E
#define INFD 3.0e38f
#define RTASK (VRAD*9 + VRAD/8)   // 292: task holding the reference candidate

#define FOOT 84             // dn tile: src region == scatter footprint (84x84)
#define FPITCH 85
#define SPITCH 88

// ---------------------------------------------------------------------------
// Stage 1: block matching. Vectorized LDS reads; barrier-light selection:
// per-wave top-16 (shfl only) + single merge by wave 0. 2 barriers total.
// ---------------------------------------------------------------------------
__global__ __launch_bounds__(256, 5)
void bm_kernel(const float* __restrict__ y, int* __restrict__ inds)
{
    __shared__ float win[WROWS][WPITCH];   // 25.2 KB
    __shared__ float candv[4][16];
    __shared__ int   candi[4][16];

    const int blk = blockIdx.x;
    const int n   = blk / (HREF*WREF);
    const int rem = blk % (HREF*WREF);
    const int hr  = (rem / WREF) * STRIDE_S;
    const int wr  = (rem % WREF) * STRIDE_S;
    const float* img = y + n * HH * WW;
    const int tid = threadIdx.x;

    for (int t = tid; t < WROWS * WPITCH; t += 256) {
        int r = t / WPITCH, c = t % WPITCH;
        int gr = hr - VRAD + r, gc = wr - VRAD + c;
        float v = 0.f;
        if (c < WROWS && gr >= 0 && gr < HH && gc >= 0 && gc < WW)
            v = img[gr * WW + gc];
        win[r][c] = v;
    }
    __syncthreads();

    float d[3][8];
#pragma unroll
    for (int s = 0; s < 3; s++)
#pragma unroll
        for (int c = 0; c < 8; c++) d[s][c] = INFD;

#pragma unroll
    for (int s = 0; s < 3; s++) {
        int task = tid + (s << 8);
        if (task < NTASK) {
            int drx = task / 9;
            int c0  = (task % 9) * 8;
            int rr  = hr + drx - VRAD;
            bool rowok = (rr >= 0 && rr <= HH - PP);
            if (rowok) {
                float dot[8];
                float colsq[18];
#pragma unroll
                for (int c = 0; c < 8; c++) dot[c] = 0.f;
#pragma unroll
                for (int j2 = 0; j2 < 18; j2++) colsq[j2] = 0.f;
                for (int a = 0; a < PP; a++) {
                    const float4* w4 = reinterpret_cast<const float4*>(&win[drx + a][c0]);
                    float4 A0 = w4[0], A1 = w4[1], A2 = w4[2], A3 = w4[3];
                    float2 A4 = *reinterpret_cast<const float2*>(&win[drx + a][c0 + 16]);
                    float wv[18] = {A0.x,A0.y,A0.z,A0.w, A1.x,A1.y,A1.z,A1.w,
                                    A2.x,A2.y,A2.z,A2.w, A3.x,A3.y,A3.z,A3.w,
                                    A4.x,A4.y};
                    const float4* r4 = reinterpret_cast<const float4*>(&win[VRAD + a][VRAD]);
                    float4 R0 = r4[0], R1 = r4[1];
                    float2 R2 = *reinterpret_cast<const float2*>(&win[VRAD + a][VRAD + 8]);
                    float  R3 = win[VRAD + a][VRAD + 10];
                    float rv[11] = {R0.x,R0.y,R0.z,R0.w, R1.x,R1.y,R1.z,R1.w,
                                    R2.x,R2.y, R3};
#pragma unroll
                    for (int j2 = 0; j2 < 18; j2++) colsq[j2] += wv[j2] * wv[j2];
#pragma unroll
                    for (int b = 0; b < PP; b++) {
#pragma unroll
                        for (int c = 0; c < 8; c++)
                            dot[c] += wv[b + c] * rv[b];
                    }
                }
#pragma unroll
                for (int j2 = 1; j2 < 18; j2++) colsq[j2] += colsq[j2 - 1];
#pragma unroll
                for (int c = 0; c < 8; c++) {
                    int dcx = c0 + c;
                    int cc  = wr + dcx - VRAD;
                    float norm = colsq[c + 10] - (c ? colsq[c - 1] : 0.f);
                    if (dcx < WINW && cc >= 0 && cc <= WW - PP)
                        d[s][c] = norm - 2.f * dot[c];
                }
            }
            if (task == RTASK) d[s][0] = -INFD;
        }
    }

    float lval = INFD; int lidx = 0;
#pragma unroll
    for (int s = 0; s < 3; s++)
#pragma unroll
        for (int c = 0; c < 8; c++)
            if (d[s][c] < lval) { lval = d[s][c]; lidx = (s << 3) | c; }

    // --- per-wave top-16: no barriers, shfl-only ---
    const int wvid = tid >> 6, lane = tid & 63;
    for (int sel = 0; sel < KSIM; sel++) {
        float rv = lval;
        int   ri = ((tid + ((lidx >> 3) << 8)) << 3) | (lidx & 7);  // task*8+c
#pragma unroll
        for (int off = 32; off > 0; off >>= 1) {
            float ov = __shfl_down(rv, off);
            int   oi = __shfl_down(ri, off);
            if (ov < rv) { rv = ov; ri = oi; }
        }
        if (lane == 0) { candv[wvid][sel] = rv; candi[wvid][sel] = ri; }
        int bi = __shfl(ri, 0);
        int otid = (bi >> 3) & 255;
        if (tid == otid) {          // owner invalidates + rescans registers
            int code = (((bi >> 3) >> 8) << 3) | (bi & 7);
            lval = INFD; lidx = 0;
#pragma unroll
            for (int s = 0; s < 3; s++)
#pragma unroll
                for (int c = 0; c < 8; c++) {
                    if (((s << 3) | c) == code) d[s][c] = INFD;
                    if (d[s][c] < lval) { lval = d[s][c]; lidx = (s << 3) | c; }
                }
        }
    }
    __syncthreads();

    // --- wave 0 merges 4x16 candidates (shfl-only) ---
    if (wvid == 0) {
        float v  = candv[lane >> 4][lane & 15];
        int   ci = candi[lane >> 4][lane & 15];
        for (int sel = 0; sel < KSIM; sel++) {
            float rv = v; int ri = ci; int rl = lane;
#pragma unroll
            for (int off = 32; off > 0; off >>= 1) {
                float ov = __shfl_down(rv, off);
                int   oi = __shfl_down(ri, off);
                int   ol = __shfl_down(rl, off);
                if (ov < rv) { rv = ov; ri = oi; rl = ol; }
            }
            int bi = __shfl(ri, 0);
            int bl = __shfl(rl, 0);
            if (lane == 0) {
                int task2 = bi >> 3;
                int drx = task2 / 9, dcx = (task2 % 9) * 8 + (bi & 7);
                inds[blk * KSIM + sel] =
                    (hr + drx - VRAD) * NPOS + (wr + dcx - VRAD);
            }
            if (lane == bl) v = INFD;
        }
    }
}

// ---------------------------------------------------------------------------
// Stage 2+3: tiled denoise (16 groups, 512 threads). Src staged in LDS,
// (g,entry) Q build, lockstep GJ inversion, theta/weights in LDS; xhat
// re-mapped to thread=(g, pixel-pair) -> no spills; LDS-atomic accumulate,
// single flush.
// ---------------------------------------------------------------------------
__global__ __launch_bounds__(512, 1)
void dn_kernel(const float* __restrict__ y, const int* __restrict__ inds,
               float2* __restrict__ nd, int R)
{
    __shared__ float  src[FOOT][SPITCH];     // 29.6 KB
    __shared__ float2 acc[FOOT][FPITCH];     // 57.1 KB
    __shared__ float  Qm[16][16][17];        // 17.4 KB (Q -> Qinv -> theta)
    __shared__ float  s1[16][16];
    __shared__ float  s2[16];
    __shared__ float  wl[16][16];
    __shared__ short  pr_[16][16], pc_[16][16];

    const int blk = blockIdx.x;
    const int n  = blk / 100;
    const int tr = blk % 100;
    const int ti = tr / 10, tj = tr % 10;
    const int r0 = 12*ti - VRAD, c0 = 12*tj - VRAD;
    const int tid = threadIdx.x;
    const float* img = y + n * HH * WW;

    if (tid < 256) {
        int g = tid >> 4, m = tid & 15;
        int gg = n*(HREF*WREF) + (ti*4 + (g >> 2))*WREF + (tj*4 + (g & 3));
        int idx = inds[gg*KSIM + m];
        pr_[g][m] = (short)(idx / NPOS);
        pc_[g][m] = (short)(idx % NPOS);
    }
    for (int t = tid; t < FOOT*FOOT; t += 512) {
        int rr = t / FOOT, cc = t % FOOT;
        int gr = r0 + rr, gc = c0 + cc;
        float v = 0.f;
        if (gr >= 0 && gr < HH && gc >= 0 && gc < WW) v = img[gr*WW + gc];
        src[rr][cc] = v;
    }
    for (int t = tid; t < FOOT*FPITCH; t += 512)
        acc[t/FPITCH][t%FPITCH] = make_float2(0.f, 0.f);
    __syncthreads();

    // ---- Q: 16 groups x 136 triangle entries ----
    for (int k = 0; k < 5; k++) {
        int task = tid + k*512;
        if (task < 16*136) {
            int g = task / 136, e = task % 136;
            int i = (int)((sqrtf(8.f*(float)e + 1.f) - 1.f) * 0.5f + 1e-4f);
            int j = e - i*(i+1)/2;
            int ari = pr_[g][i] - r0, aci = pc_[g][i] - c0;
            int arj = pr_[g][j] - r0, acj = pc_[g][j] - c0;
            float s = (i == j) ? EPS_E : 0.f;
            for (int a = 0; a < PP; a++) {
                const float* Ri = &src[ari + a][aci];
                const float* Rj = &src[arj + a][acj];
#pragma unroll
                for (int b = 0; b < PP; b++) s += Ri[b] * Rj[b];
            }
            Qm[g][i][j] = s;
            Qm[g][j][i] = s;
        }
    }
    __syncthreads();

    // ---- lockstep Gauss-Jordan inversion (16 SPD matrices) ----
    const int uu = tid >> 8, ii = (tid >> 4) & 15, jj = tid & 15;
    for (int ks = 0; ks < 16; ks++) {
        float fA[8], rk[8], pv[8], aij[8];
#pragma unroll
        for (int k = 0; k < 8; k++) {
            int g = uu + 2*k;
            fA[k]  = Qm[g][ii][ks];
            rk[k]  = Qm[g][ks][jj];
            pv[k]  = Qm[g][ks][ks];
            aij[k] = Qm[g][ii][jj];
        }
        __syncthreads();
#pragma unroll
        for (int k = 0; k < 8; k++) {
            int g = uu + 2*k;
            float inv = 1.f / pv[k];
            float nv;
            if (ii == ks) nv = (jj == ks) ? inv : rk[k] * inv;
            else          nv = (jj == ks) ? -fA[k] * inv : aij[k] - fA[k] * rk[k] * inv;
            Qm[g][ii][jj] = nv;
        }
        __syncthreads();
    }

    // ---- s1, s2, theta (in-place), weights ----
    if (tid < 256) {
        int g = tid >> 4, a = tid & 15;
        float s = 0.f;
#pragma unroll
        for (int b = 0; b < 16; b++) s += Qm[g][a][b];
        s1[g][a] = s;
    }
    __syncthreads();
    if (tid < 16) {
        float s = 0.f;
#pragma unroll
        for (int a = 0; a < 16; a++) s += s1[tid][a];
        s2[tid] = s;
    }
    __syncthreads();
#pragma unroll
    for (int k = 0; k < 8; k++) {
        int g = uu + 2*k;
        float t = ((ii == jj) ? 1.f : 0.f)
                - (Qm[g][ii][jj] - s1[g][ii]*s1[g][jj]/s2[g]) * DE_C;
        Qm[g][ii][jj] = t;
    }
    __syncthreads();
    if (tid < 256) {
        int g = tid >> 4, r = tid & 15;
        float s = 0.f;
#pragma unroll
        for (int m2 = 0; m2 < 16; m2++) { float t = Qm[g][m2][r]; s += t*t; }
        s = fminf(fmaxf(s, 1.f/16.f), 1.f);
        wl[g][r] = 1.f / s;
    }
    __syncthreads();

    // ---- xhat: thread = (g, pixel-pair). 16*61 = 976 tasks, 2 rounds ----
    for (int it = 0; it < 2; it++) {
        int task = tid + it*512;
        if (task < 16*61) {
            int g = task / 61, s = task % 61;
            int pxa = 2*s;
            bool okB = (pxa + 1 < 121);
            int dra = pxa / 11, dca = pxa % 11;
            int drb = dra, dcb = dca + 1;
            if (dcb == 11) { drb = dra + 1; dcb = 0; }
            if (!okB) { drb = dra; dcb = dca; }

            int baseS[16];
#pragma unroll
            for (int m = 0; m < 16; m++)
                baseS[m] = ((int)pr_[g][m] - r0) * SPITCH + ((int)pc_[g][m] - c0);

            const float* sf = &src[0][0];
            float xhA[16], xhB[16];
#pragma unroll
            for (int r = 0; r < 16; r++) { xhA[r] = 0.f; xhB[r] = 0.f; }
            const int offA = dra*SPITCH + dca, offB = drb*SPITCH + dcb;
#pragma unroll
            for (int m = 0; m < 16; m++) {
                float yvA = sf[baseS[m] + offA];
                float yvB = sf[baseS[m] + offB];
#pragma unroll
                for (int r = 0; r < 16; r++) {
                    float t = Qm[g][m][r];     // theta[m][r], broadcast read
                    xhA[r] += t * yvA;
                    xhB[r] += t * yvB;
                }
            }
#pragma unroll
            for (int r = 0; r < 16; r++) {
                float wv2 = wl[g][r];
                int ar = (int)pr_[g][r] - r0, ac = (int)pc_[g][r] - c0;
                float* cA = (float*)&acc[ar + dra][ac + dca];
                __hip_atomic_fetch_add(cA,     wv2 * xhA[r],
                    __ATOMIC_RELAXED, __HIP_MEMORY_SCOPE_WORKGROUP);
                __hip_atomic_fetch_add(cA + 1, wv2,
                    __ATOMIC_RELAXED, __HIP_MEMORY_SCOPE_WORKGROUP);
                if (okB) {
                    float* cB = (float*)&acc[ar + drb][ac + dcb];
                    __hip_atomic_fetch_add(cB,     wv2 * xhB[r],
                        __ATOMIC_RELAXED, __HIP_MEMORY_SCOPE_WORKGROUP);
                    __hip_atomic_fetch_add(cB + 1, wv2,
                        __ATOMIC_RELAXED, __HIP_MEMORY_SCOPE_WORKGROUP);
                }
            }
        }
    }
    __syncthreads();

    // ---- flush tile to global (skip empty cells) ----
    float2* ndI = nd + ((size_t)(blk & (R - 1)) * NIMG + n) * HH * WW;
    for (int t = tid; t < FOOT * FOOT; t += 512) {
        int rr = t / FOOT, cc = t % FOOT;
        float2 v = acc[rr][cc];
        if (v.y != 0.f) {
            int px = (r0 + rr) * WW + (c0 + cc);
#if defined(__has_builtin) && __has_builtin(__builtin_amdgcn_global_atomic_fadd_v2f32)
            typedef float v2f __attribute__((ext_vector_type(2)));
            __builtin_amdgcn_global_atomic_fadd_v2f32((v2f*)&ndI[px], (v2f){v.x, v.y});
#else
            atomicAdd(&ndI[px].x, v.x);
            atomicAdd(&ndI[px].y, v.y);
#endif
        }
    }
}

// ---------------------------------------------------------------------------
// Stage 4: out = sum_r num_r / sum_r den_r
// ---------------------------------------------------------------------------
__global__ __launch_bounds__(256)
void fin_kernel(const float2* __restrict__ nd, float* __restrict__ out, int R)
{
    int t = blockIdx.x * 256 + threadIdx.x;
    if (t < NIMG * HH * WW) {
        float sn = 0.f, sd = 0.f;
        for (int r = 0; r < R; r++) {
            float2 v = nd[(size_t)r * NIMG * HH * WW + t];
            sn += v.x; sd += v.y;
        }
        out[t] = sn / sd;
    }
}

extern "C" void kernel_launch(void* const* d_in, const int* in_sizes, int n_in,
                              void* d_out, int out_size, void* d_ws, size_t ws_size,
                              hipStream_t stream)
{
    const float* y = (const float*)d_in[0];
    float* out = (float*)d_out;

    size_t indsBytes = (size_t)NGROUP * KSIM * sizeof(int);
    size_t perRep    = (size_t)NIMG * HH * WW * sizeof(float2);
    int R = 1;
    while (R < 4 && indsBytes + perRep * (size_t)(R * 2) <= ws_size) R <<= 1;

    float2* nd  = (float2*)d_ws;
    int*    inds = (int*)((char*)d_ws + perRep * (size_t)R);

    hipMemsetAsync(nd, 0, perRep * (size_t)R, stream);
    bm_kernel<<<NGROUP, 256, 0, stream>>>(y, inds);
    dn_kernel<<<NIMG * 100, 512, 0, stream>>>(y, inds, nd, R);
    fin_kernel<<<(NIMG * HH * WW + 255) / 256, 256, 0, stream>>>(nd, out, R);
}